// Round 6
// baseline (115.115 us; speedup 1.0000x reference)
//
#include <hip/hip_runtime.h>

#define CCH 128
#define SV 24
#define NVOX 13824   // 24^3

typedef unsigned short u16;
typedef unsigned int   u32;

__device__ __forceinline__ u16 f2bf(float f) {
    u32 x = __float_as_uint(f);
    u32 r = x + 0x7fffu + ((x >> 16) & 1u);   // round-to-nearest-even
    return (u16)(r >> 16);
}
// unpack uint2 (4 packed bf16) -> 4 floats (elem i at u16 index i, LE)
__device__ __forceinline__ void cvt4b(uint2 r, float* f) {
    f[0] = __uint_as_float(r.x << 16); f[1] = __uint_as_float(r.x & 0xffff0000u);
    f[2] = __uint_as_float(r.y << 16); f[3] = __uint_as_float(r.y & 0xffff0000u);
}

// ---------------------------------------------------------------------------
// Projection GEMM: C[vox][o] = sum_c X[c][vox] * W[o][c] + b[o].
// blockIdx.y = m in {q,k,v}; blockIdx.z = o-half. Block = 64 vox x 64 o,
// K-tile 32, thread tile 4 vox x 4 o. LDS: Xs 8 KB + Ws 8 KB (transposed).
// q -> d_out fp32; k -> ws fp32; v -> ws bf16. Pad row at vox==NVOX.
// Grid (216, 3, 2).
// ---------------------------------------------------------------------------
__global__ __launch_bounds__(256) void proj_kernel(
    const float* __restrict__ x,
    const float* __restrict__ wq, const float* __restrict__ bq,
    const float* __restrict__ wk, const float* __restrict__ bk,
    const float* __restrict__ wv, const float* __restrict__ bv,
    const float* __restrict__ relh, const float* __restrict__ relw,
    const float* __restrict__ reld,
    float* __restrict__ qout, float* __restrict__ kws, u16* __restrict__ vws,
    float* __restrict__ biasW)
{
    const int m = blockIdx.y;                  // 0=q 1=k 2=v
    const float* __restrict__ w = (m == 0) ? wq : (m == 1) ? wk : wv;
    const float* __restrict__ b = (m == 0) ? bq : (m == 1) ? bk : bv;

    __shared__ float Xs[32][64];
    __shared__ float Ws[32][64];

    const int tid  = threadIdx.x;
    const int vox0 = blockIdx.x * 64;
    const int oblk = blockIdx.z * 64;
    const int v0   = (tid & 15) * 4;           // compute: voxel group
    const int o0   = (tid >> 4) * 4;           // compute: output group (0..60)

    // staging indices
    const int xc  = tid >> 3;                  // 0..31  (c-row)
    const int xv  = (tid & 7) * 4;             // 0,4,..,28
    const int wo  = tid & 63;                  // 0..63  (o-row within half)
    const int wkh = (tid >> 6) * 8;            // 0,8,16,24

    float acc[4][4] = {{0.f}};

    for (int k0 = 0; k0 < CCH; k0 += 32) {
        // X slice: 32 c-rows x 64 vox, coalesced
        {
            const float* src = x + (size_t)(k0 + xc) * NVOX + vox0 + xv;
            const float4 a0 = *(const float4*)src;
            const float4 a1 = *(const float4*)(src + 32);
            *(float4*)&Xs[xc][xv]      = a0;
            *(float4*)&Xs[xc][xv + 32] = a1;
        }
        // W slice: row o=oblk+wo, cols k0+wkh..+7 -> transposed Ws[k][o]
        {
            const float* src = w + (size_t)(oblk + wo) * CCH + k0 + wkh;
            const float4 b0 = *(const float4*)src;
            const float4 b1 = *(const float4*)(src + 4);
            Ws[wkh + 0][wo] = b0.x; Ws[wkh + 1][wo] = b0.y;
            Ws[wkh + 2][wo] = b0.z; Ws[wkh + 3][wo] = b0.w;
            Ws[wkh + 4][wo] = b1.x; Ws[wkh + 5][wo] = b1.y;
            Ws[wkh + 6][wo] = b1.z; Ws[wkh + 7][wo] = b1.w;
        }
        __syncthreads();

#pragma unroll
        for (int k = 0; k < 32; ++k) {
            const float4 xf = *(const float4*)&Xs[k][v0];
            const float4 wf = *(const float4*)&Ws[k][o0];
            const float xr[4] = {xf.x, xf.y, xf.z, xf.w};
            const float wr[4] = {wf.x, wf.y, wf.z, wf.w};
#pragma unroll
            for (int vv = 0; vv < 4; ++vv)
#pragma unroll
                for (int oo = 0; oo < 4; ++oo)
                    acc[vv][oo] = fmaf(xr[vv], wr[oo], acc[vv][oo]);
        }
        __syncthreads();
    }

    const float4 bf = *(const float4*)(b + oblk + o0);
    const float br[4] = {bf.x, bf.y, bf.z, bf.w};

#pragma unroll
    for (int vv = 0; vv < 4; ++vv) {
        float r[4];
#pragma unroll
        for (int oo = 0; oo < 4; ++oo) r[oo] = acc[vv][oo] + br[oo];
        const size_t row = (size_t)(vox0 + v0 + vv) * CCH + oblk + o0;
        if (m == 0) {
            float4 st = {r[0], r[1], r[2], r[3]};
            *(float4*)(qout + row) = st;
        } else if (m == 1) {
            float4 st = {r[0], r[1], r[2], r[3]};
            *(float4*)(kws + row) = st;
        } else {
            uint2 st;
            st.x = (u32)f2bf(r[0]) | ((u32)f2bf(r[1]) << 16);
            st.y = (u32)f2bf(r[2]) | ((u32)f2bf(r[3]) << 16);
            *(uint2*)(vws + row) = st;
        }
    }

    if (blockIdx.x == 0 && blockIdx.z == 0) {
        if (m == 1 && tid < CCH) kws[(size_t)NVOX * CCH + tid] = bk[tid];
        if (m == 2 && tid < CCH) vws[(size_t)NVOX * CCH + tid] = f2bf(bv[tid]);
        if (m == 1 && tid < 27) {
            const int i = tid / 9, j = (tid / 3) % 3, l = tid % 3;
            float s = 0.f;
            for (int c = 0; c < 64; ++c)
                s += relh[c * 3 + i] + relw[c * 3 + j] + reld[c * 3 + l];
            biasW[tid] = s;
        }
    }
}

// ---------------------------------------------------------------------------
// neighbor row offset for window slot s (folds at compile time after unroll)
// ---------------------------------------------------------------------------
__device__ __forceinline__ int nbr_off(int h, int w, int d, int s, int ch) {
    const int nh = h + s / 9 - 1;
    const int nw = w + (s / 3) % 3 - 1;
    const int nd = d + s % 3 - 1;
    const bool ok = ((unsigned)nh < (unsigned)SV) &&
                    ((unsigned)nw < (unsigned)SV) &&
                    ((unsigned)nd < (unsigned)SV);
    const int idx = ok ? ((nh * SV + nw) * SV + nd) : NVOX;
    return idx * CCH + ch;
}

// ---------------------------------------------------------------------------
// Attention: 32 lanes/voxel (4 ch each), 8 voxels per 256-thr block.
// q fp32 from d_out (overwritten in place); k fp32 gathers (float4/lane/row),
// v bf16 gathers (uint2/lane/row), batches of 9 for latency overlap.
// Grid 1728.
// ---------------------------------------------------------------------------
__global__ __launch_bounds__(256) void attn_kernel(
    float* __restrict__ qo, const float* __restrict__ kws,
    const u16* __restrict__ vws, const float* __restrict__ biasW)
{
    const int tid  = threadIdx.x;
    const int lane = tid & 31;
    const int vox  = blockIdx.x * 8 + (tid >> 5);
    const int h    = vox / 576;
    const int rem  = vox - h * 576;
    const int w    = rem / 24;
    const int d    = rem - w * 24;
    const int ch   = lane * 4;

    const float4 q4 = *(const float4*)(qo + (size_t)vox * CCH + ch);
    const float qr[4] = {q4.x, q4.y, q4.z, q4.w};

    float qs = qr[0] + qr[1] + qr[2] + qr[3];
#pragma unroll
    for (int mm = 1; mm < 32; mm <<= 1) qs += __shfl_xor(qs, mm, 64);

    float ps[27];
    // ---- QK phase: 3 batches of 9 rows (fp32 k) ----
#pragma unroll
    for (int sb = 0; sb < 27; sb += 9) {
        float4 kf[9];
#pragma unroll
        for (int j = 0; j < 9; ++j)
            kf[j] = *(const float4*)(kws + nbr_off(h, w, d, sb + j, ch));
#pragma unroll
        for (int j = 0; j < 9; ++j) {
            float p = qr[0] * kf[j].x;
            p = fmaf(qr[1], kf[j].y, p);
            p = fmaf(qr[2], kf[j].z, p);
            p = fmaf(qr[3], kf[j].w, p);
            ps[sb + j] = p;
        }
    }

#pragma unroll
    for (int mm = 1; mm < 32; mm <<= 1) {
#pragma unroll
        for (int s = 0; s < 27; ++s) ps[s] += __shfl_xor(ps[s], mm, 64);
    }

#pragma unroll
    for (int s = 0; s < 27; ++s) ps[s] = fmaf(qs, biasW[s], ps[s]);

    float mx = ps[0];
#pragma unroll
    for (int s = 1; s < 27; ++s) mx = fmaxf(mx, ps[s]);
    float sum = 0.f;
#pragma unroll
    for (int s = 0; s < 27; ++s) { ps[s] = __expf(ps[s] - mx); sum += ps[s]; }
    const float inv = 1.f / sum;
#pragma unroll
    for (int s = 0; s < 27; ++s) ps[s] *= inv;

    // ---- PV phase: 3 batches of 9 rows (bf16 v) ----
    float o[4] = {0.f, 0.f, 0.f, 0.f};
#pragma unroll
    for (int sb = 0; sb < 27; sb += 9) {
        uint2 vf[9];
#pragma unroll
        for (int j = 0; j < 9; ++j)
            vf[j] = *(const uint2*)(vws + nbr_off(h, w, d, sb + j, ch));
#pragma unroll
        for (int j = 0; j < 9; ++j) {
            float f[4];
            cvt4b(vf[j], f);
            const float a = ps[sb + j];
            o[0] = fmaf(a, f[0], o[0]); o[1] = fmaf(a, f[1], o[1]);
            o[2] = fmaf(a, f[2], o[2]); o[3] = fmaf(a, f[3], o[3]);
        }
    }

    float4 st = {o[0], o[1], o[2], o[3]};
    *(float4*)(qo + (size_t)vox * CCH + ch) = st;
}

// ---------------------------------------------------------------------------
extern "C" void kernel_launch(void* const* d_in, const int* in_sizes, int n_in,
                              void* d_out, int out_size, void* d_ws,
                              size_t ws_size, hipStream_t stream)
{
    const float* x    = (const float*)d_in[0];
    const float* wq   = (const float*)d_in[1];
    const float* bq   = (const float*)d_in[2];
    const float* wk   = (const float*)d_in[3];
    const float* bk   = (const float*)d_in[4];
    const float* wv   = (const float*)d_in[5];
    const float* bv   = (const float*)d_in[6];
    const float* relh = (const float*)d_in[7];
    const float* relw = (const float*)d_in[8];
    const float* reld = (const float*)d_in[9];

    float* kws   = (float*)d_ws;                       // (NVOX+1)*128 fp32
    u16*   vws   = (u16*)(kws + (size_t)(NVOX + 1) * CCH);  // bf16
    float* biasW = (float*)(vws + (size_t)(NVOX + 1) * CCH); // 27 fp32

    dim3 pgrid(NVOX / 64, 3, 2);
    proj_kernel<<<pgrid, 256, 0, stream>>>(x, wq, bq, wk, bk, wv, bv,
                                           relh, relw, reld,
                                           (float*)d_out, kws, vws, biasW);
    attn_kernel<<<NVOX / 8, 256, 0, stream>>>((float*)d_out, kws, vws, biasW);
}